// Round 12
// baseline (143.087 us; speedup 1.0000x reference)
//
#include <hip/hip_runtime.h>
#include <hip/hip_bf16.h>

#define BN_EPS 1e-5f
#define MG 2                 // 16-node tiles per k_node block

typedef short bf16x8 __attribute__((ext_vector_type(8)));   // also generic short8
typedef float f32x4  __attribute__((ext_vector_type(4)));

static __device__ __forceinline__ unsigned short f2bf(float f) {
    union { float f; unsigned int u; } v; v.f = f;
    unsigned int u = v.u;
    unsigned int r = (u + 0x7FFFu + ((u >> 16) & 1u)) >> 16;   // RNE
    return (unsigned short)r;
}

static __device__ __forceinline__ unsigned short f2bf_hw(float f) {
    __hip_bfloat16 b = __float2bfloat16(f);
    union { __hip_bfloat16 b; unsigned short u; } v; v.b = b;
    return v.u;
}

static __device__ __forceinline__ unsigned short f2h(float f) {   // f32 -> f16 bits (RNE)
    union { _Float16 h; unsigned short u; } v; v.h = (_Float16)f;
    return v.u;
}

static __device__ __forceinline__ float h2f(short s) {            // f16 bits -> f32
    union { short s; _Float16 h; } v; v.s = s;
    return (float)v.h;
}

// ---------------- prep kernel: weights only ----------------
__global__ __launch_bounds__(256) void k_prep(
        const float* __restrict__ W0, const float* __restrict__ b0,
        const float* __restrict__ W1, const float* __restrict__ b1,
        const float* __restrict__ W2, const float* __restrict__ b2,
        const float* __restrict__ g0, const float* __restrict__ be0,
        const float* __restrict__ m0, const float* __restrict__ v0,
        const float* __restrict__ g1, const float* __restrict__ be1,
        const float* __restrict__ m1, const float* __restrict__ v1,
        const float* __restrict__ g2, const float* __restrict__ be2,
        const float* __restrict__ m2, const float* __restrict__ v2,
        unsigned short* __restrict__ W0sw, unsigned short* __restrict__ W1sw,
        float* __restrict__ b0f, float* __restrict__ b1f,
        float* __restrict__ w2f, float* __restrict__ b2f) {
    int br = blockIdx.x;
    const int tid = threadIdx.x;

    if (br < 128) {                        // ---- W0sw (BN0 scale folded) ----
        int t = br * 256 + tid;
        int j = t & 7, lane = (t >> 3) & 63, nt = (t >> 9) & 7, kb = t >> 12;
        int k = kb * 32 + (lane >> 4) * 8 + j;
        int n = nt * 16 + (lane & 15);
        float s = g0[k] * rsqrtf(v0[k] + BN_EPS);
        W0sw[t] = f2bf(W0[n * 256 + k] * s);
        return;
    }
    br -= 128;
    if (br < 64) {                         // ---- W1sw ----
        int t = br * 256 + tid;
        int j = t & 7, lane = (t >> 3) & 63, nt = (t >> 9) & 7, kb = t >> 12;
        int k = kb * 32 + (lane >> 4) * 8 + j;
        int n = nt * 16 + (lane & 15);
        float s = g1[k] * rsqrtf(v1[k] + BN_EPS);
        W1sw[t] = f2bf(W1[n * 128 + k] * s);
        return;
    }
    br -= 64;
    {                                      // ---- folded biases (row = br, 0..127) ----
        if (tid >= 64) return;
        const int i = br, lane = tid;
        float s0 = 0.f;
#pragma unroll
        for (int c = 0; c < 4; c++) {
            int k = c * 64 + lane;
            float sc = g0[k] * rsqrtf(v0[k] + BN_EPS);
            s0 += W0[i * 256 + k] * (be0[k] - m0[k] * sc);
        }
        float s1 = 0.f;
#pragma unroll
        for (int c = 0; c < 2; c++) {
            int k = c * 64 + lane;
            float sc = g1[k] * rsqrtf(v1[k] + BN_EPS);
            s1 += W1[i * 128 + k] * (be1[k] - m1[k] * sc);
        }
        float s2 = 0.f;
        if (i == 0) {
#pragma unroll
            for (int c = 0; c < 2; c++) {
                int k = c * 64 + lane;
                float sc = g2[k] * rsqrtf(v2[k] + BN_EPS);
                s2 += W2[k] * (be2[k] - m2[k] * sc);
            }
        }
#pragma unroll
        for (int off = 1; off < 64; off <<= 1) {
            s0 += __shfl_xor(s0, off);
            s1 += __shfl_xor(s1, off);
            s2 += __shfl_xor(s2, off);
        }
        if (lane == 0) {
            b0f[i] = b0[i] + s0;
            b1f[i] = b1[i] + s1;
            w2f[i] = W2[i] * (g2[i] * rsqrtf(v2[i] + BN_EPS));
            if (i == 0) b2f[0] = b2[0] + s2;
        }
    }
}

// ---------------- node projection: UV[n][0..127]=f16(h@W0s^T+b0f), [128..255]=f16(h@W0d^T) ----
__global__ __launch_bounds__(256) void k_node(
        const float* __restrict__ h,
        const unsigned short* __restrict__ W0sw,
        const float* __restrict__ b0f,
        unsigned short* __restrict__ UV, int N) {
    const int tid  = threadIdx.x;
    const int wave = tid >> 6;
    const int lane = tid & 63;
    const int quad = lane >> 4;
    const int m    = lane & 15;
    const int nb   = blockIdx.x * 32;

    bf16x8 B0[8][2];
#pragma unroll
    for (int kb = 0; kb < 8; kb++)
#pragma unroll
        for (int hh = 0; hh < 2; hh++)
            B0[kb][hh] = *(const bf16x8*)(W0sw + ((kb * 8 + (wave * 2 + hh)) * 64 + lane) * 8);

    float b0v[2];
#pragma unroll
    for (int hh = 0; hh < 2; hh++) b0v[hh] = b0f[(wave * 2 + hh) * 16 + m];

    f32x4 au[MG][2], av[MG][2];
#pragma unroll
    for (int g = 0; g < MG; g++)
#pragma unroll
        for (int hh = 0; hh < 2; hh++) {
            au[g][hh] = (f32x4){0.f, 0.f, 0.f, 0.f};
            av[g][hh] = (f32x4){0.f, 0.f, 0.f, 0.f};
        }

#pragma unroll
    for (int g = 0; g < MG; g++) {
        int nrow = nb + g * 16 + m; if (nrow >= N) nrow = N - 1;
        const float* hrow = h + (size_t)nrow * 128;
#pragma unroll
        for (int kb = 0; kb < 4; kb++) {
            const float* hp = hrow + kb * 32 + quad * 8;
            f32x4 f0 = *(const f32x4*)hp;
            f32x4 f1 = *(const f32x4*)(hp + 4);
            bf16x8 a;
            a[0] = (short)f2bf_hw(f0[0]); a[1] = (short)f2bf_hw(f0[1]);
            a[2] = (short)f2bf_hw(f0[2]); a[3] = (short)f2bf_hw(f0[3]);
            a[4] = (short)f2bf_hw(f1[0]); a[5] = (short)f2bf_hw(f1[1]);
            a[6] = (short)f2bf_hw(f1[2]); a[7] = (short)f2bf_hw(f1[3]);
#pragma unroll
            for (int hh = 0; hh < 2; hh++) {
                au[g][hh] = __builtin_amdgcn_mfma_f32_16x16x32_bf16(a, B0[kb][hh],     au[g][hh], 0, 0, 0);
                av[g][hh] = __builtin_amdgcn_mfma_f32_16x16x32_bf16(a, B0[kb + 4][hh], av[g][hh], 0, 0, 0);
            }
        }
    }

#pragma unroll
    for (int g = 0; g < MG; g++)
#pragma unroll
        for (int hh = 0; hh < 2; hh++) {
            int col = (wave * 2 + hh) * 16 + m;
#pragma unroll
            for (int r = 0; r < 4; r++) {
                int node = nb + g * 16 + quad * 4 + r;
                if (node < N) {
                    UV[(size_t)node * 256 + col]       = f2h(au[g][hh][r] + b0v[hh]);
                    UV[(size_t)node * 256 + 128 + col] = f2h(av[g][hh][r]);
                }
            }
        }
}

// ---------------- edge kernel: W1-split pairs + 2-deep UV prefetch (A/B contexts) ----
// R11 post-mortem: spill fixed but NEUTRAL — occupancy exonerated. Remaining theory:
// gather is miss-CONCURRENCY-limited (~12 outstanding 64B lines/CU from Little's law on
// R6's 28 MB @ 700 GB/s). Probe: unroll by 2 groups with static A/B register contexts
// (rule #20: no runtime-indexed buffers) -> 8 UV loads in flight per wave (2x R11) and
// issue->consume distance of a full A+B body. aS/pS parity is static: A->slot 0, B->slot 1.
// If concurrency-limited: k_edge 36 -> ~20-26 us. If neutral: HW wall; next = edge sort
// or roofline. Tripwires: VGPR<=170, WRITE_SIZE ~1250 KB, absmax 0.015625.
__global__ __launch_bounds__(256, 3) void k_edge(
        const int* __restrict__ src, const int* __restrict__ dst,
        const unsigned short* __restrict__ UV,
        const unsigned short* __restrict__ W1sw,
        const float* __restrict__ b1f, const float* __restrict__ w2f,
        const float* __restrict__ b2fp,
        float* __restrict__ out, int E, int nG) {
    __shared__ __align__(16) unsigned short aS[2][2][4][64][8];  // [ctx A/B][pair][kb][lane][8] = 16 KB
    __shared__ float pS[2][2][2][16];                            // [ctx][pair][hf][edge] = 512 B

    const int tid  = threadIdx.x;
    const int wave = tid >> 6;
    const int lane = tid & 63;
    const int q    = lane >> 4;
    const int m    = lane & 15;
    const int p2   = wave >> 1;     // pair index 0..1 (owns edges p2*16..+16 of the group)
    const int hf   = wave & 1;      // half: nt-range hf*4.., kb-range hf*2..
    const int kb0  = hf * 2;        // own kb: kb0, kb0+1

    // half of stage-1 weights: nt = hf*4 + i  (64 VGPR)
    bf16x8 B1h[4][4];               // [i][kb] — static indices only
#pragma unroll
    for (int i = 0; i < 4; i++)
#pragma unroll
        for (int kb = 0; kb < 4; kb++)
            B1h[i][kb] = *(const bf16x8*)(W1sw + ((kb * 8 + (hf * 4 + i)) * 64 + lane) * 8);

    float b1v[4], w2v[4];
#pragma unroll
    for (int i = 0; i < 4; i++) {
        b1v[i] = b1f[(hf * 4 + i) * 16 + m];
        w2v[i] = w2f[(hf * 4 + i) * 16 + m];
    }
    const float b2s = *b2fp;
    const int stride = gridDim.x;

    int gi = blockIdx.x;

    // A-context: groups gi, gi+2s, gi+4s, ... ; B-context: gi+s, gi+3s, ...
    bf16x8 uA0, uA1, vA0, vA1;      // UV chunks, A-stream current group
    bf16x8 uB0, uB1, vB0, vB1;      // UV chunks, B-stream current group
    int rsC, rdC;                   // idx for A-stream group+2s (resident)
    int rsD, rdD;                   // idx for B-stream group+2s (resident)

    // ---- prologue ----
    {
        int e0 = gi * 32 + p2 * 16 + m; if (e0 >= E) e0 = E - 1;
        int rs0 = src[e0], rd0 = dst[e0];
        uA0 = *(const bf16x8*)(UV + (size_t)rs0 * 256 + (kb0 + 0) * 32 + q * 8);
        uA1 = *(const bf16x8*)(UV + (size_t)rs0 * 256 + (kb0 + 1) * 32 + q * 8);
        vA0 = *(const bf16x8*)(UV + (size_t)rd0 * 256 + 128 + (kb0 + 0) * 32 + q * 8);
        vA1 = *(const bf16x8*)(UV + (size_t)rd0 * 256 + 128 + (kb0 + 1) * 32 + q * 8);

        int g1 = gi + stride; int gg1 = g1 < nG ? g1 : 0;
        int e1 = gg1 * 32 + p2 * 16 + m; if (e1 >= E) e1 = E - 1;
        int rs1 = src[e1], rd1 = dst[e1];
        uB0 = *(const bf16x8*)(UV + (size_t)rs1 * 256 + (kb0 + 0) * 32 + q * 8);
        uB1 = *(const bf16x8*)(UV + (size_t)rs1 * 256 + (kb0 + 1) * 32 + q * 8);
        vB0 = *(const bf16x8*)(UV + (size_t)rd1 * 256 + 128 + (kb0 + 0) * 32 + q * 8);
        vB1 = *(const bf16x8*)(UV + (size_t)rd1 * 256 + 128 + (kb0 + 1) * 32 + q * 8);

        int g2 = gi + 2 * stride; int gg2 = g2 < nG ? g2 : 0;
        int e2 = gg2 * 32 + p2 * 16 + m; if (e2 >= E) e2 = E - 1;
        rsC = src[e2]; rdC = dst[e2];
        int g3 = gi + 3 * stride; int gg3 = g3 < nG ? g3 : 0;
        int e3 = gg3 * 32 + p2 * 16 + m; if (e3 >= E) e3 = E - 1;
        rsD = src[e3]; rdD = dst[e3];
    }

    for (; gi < nG; gi += 2 * stride) {
        // ================= PART A: group gi (ctx 0) =================
        {
            bf16x8 aOwn0, aOwn1;
#pragma unroll
            for (int j = 0; j < 8; j++) {
                float s0 = h2f(uA0[j]) + h2f(vA0[j]);
                float s1 = h2f(uA1[j]) + h2f(vA1[j]);
                s0 = s0 > 0.f ? s0 : 0.f;
                s1 = s1 > 0.f ? s1 : 0.f;
                aOwn0[j] = (short)f2bf_hw(s0);
                aOwn1[j] = (short)f2bf_hw(s1);
            }
            *(bf16x8*)&aS[0][p2][kb0 + 0][lane][0] = aOwn0;
            *(bf16x8*)&aS[0][p2][kb0 + 1][lane][0] = aOwn1;

            // issue UV(gi+2s) into freed A-regs (idx resident)
            {
                int rs_ = rsC, rd_ = rdC;
                uA0 = *(const bf16x8*)(UV + (size_t)rs_ * 256 + (kb0 + 0) * 32 + q * 8);
                uA1 = *(const bf16x8*)(UV + (size_t)rs_ * 256 + (kb0 + 1) * 32 + q * 8);
                vA0 = *(const bf16x8*)(UV + (size_t)rd_ * 256 + 128 + (kb0 + 0) * 32 + q * 8);
                vA1 = *(const bf16x8*)(UV + (size_t)rd_ * 256 + 128 + (kb0 + 1) * 32 + q * 8);
            }
            // idx(gi+4s)
            {
                int g4 = gi + 4 * stride; int gg = g4 < nG ? g4 : 0;
                int e4 = gg * 32 + p2 * 16 + m; if (e4 >= E) e4 = E - 1;
                rsC = src[e4]; rdC = dst[e4];
            }

            asm volatile("s_waitcnt lgkmcnt(0)" ::: "memory");
            __builtin_amdgcn_s_barrier();
            __builtin_amdgcn_sched_barrier(0);

            bf16x8 a0, a1, a2, a3;
            if (hf == 0) {
                a0 = aOwn0;
                a1 = aOwn1;
                a2 = *(const bf16x8*)&aS[0][p2][2][lane][0];
                a3 = *(const bf16x8*)&aS[0][p2][3][lane][0];
            } else {
                a0 = *(const bf16x8*)&aS[0][p2][0][lane][0];
                a1 = *(const bf16x8*)&aS[0][p2][1][lane][0];
                a2 = aOwn0;
                a3 = aOwn1;
            }

            f32x4 acc[4];
#pragma unroll
            for (int i = 0; i < 4; i++) acc[i] = (f32x4){0.f, 0.f, 0.f, 0.f};
#pragma unroll
            for (int i = 0; i < 4; i++) acc[i] = __builtin_amdgcn_mfma_f32_16x16x32_bf16(a0, B1h[i][0], acc[i], 0, 0, 0);
#pragma unroll
            for (int i = 0; i < 4; i++) acc[i] = __builtin_amdgcn_mfma_f32_16x16x32_bf16(a1, B1h[i][1], acc[i], 0, 0, 0);
#pragma unroll
            for (int i = 0; i < 4; i++) acc[i] = __builtin_amdgcn_mfma_f32_16x16x32_bf16(a2, B1h[i][2], acc[i], 0, 0, 0);
#pragma unroll
            for (int i = 0; i < 4; i++) acc[i] = __builtin_amdgcn_mfma_f32_16x16x32_bf16(a3, B1h[i][3], acc[i], 0, 0, 0);

            float s[4] = {0.f, 0.f, 0.f, 0.f};
#pragma unroll
            for (int i = 0; i < 4; i++)
#pragma unroll
                for (int r = 0; r < 4; r++) {
                    float v = acc[i][r] + b1v[i];
                    v = v > 0.f ? v : 0.f;
                    s[r] += v * w2v[i];
                }
#pragma unroll
            for (int off = 1; off < 16; off <<= 1)
#pragma unroll
                for (int r = 0; r < 4; r++) s[r] += __shfl_xor(s[r], off, 16);
            if (m == 0) {
#pragma unroll
                for (int r = 0; r < 4; r++) pS[0][p2][hf][q * 4 + r] = s[r];
            }

            asm volatile("s_waitcnt lgkmcnt(0)" ::: "memory");
            __builtin_amdgcn_s_barrier();
            __builtin_amdgcn_sched_barrier(0);

            if (hf == 0 && lane < 16) {
                int e = gi * 32 + p2 * 16 + lane;
                if (e < E)
                    out[e] = pS[0][p2][0][lane] + pS[0][p2][1][lane] + b2s;
            }
        }

        // ================= PART B: group gi+stride (ctx 1) =================
        if (gi + stride < nG) {        // block-uniform guard -> barriers safe
            int gB = gi + stride;
            bf16x8 aOwn0, aOwn1;
#pragma unroll
            for (int j = 0; j < 8; j++) {
                float s0 = h2f(uB0[j]) + h2f(vB0[j]);
                float s1 = h2f(uB1[j]) + h2f(vB1[j]);
                s0 = s0 > 0.f ? s0 : 0.f;
                s1 = s1 > 0.f ? s1 : 0.f;
                aOwn0[j] = (short)f2bf_hw(s0);
                aOwn1[j] = (short)f2bf_hw(s1);
            }
            *(bf16x8*)&aS[1][p2][kb0 + 0][lane][0] = aOwn0;
            *(bf16x8*)&aS[1][p2][kb0 + 1][lane][0] = aOwn1;

            // issue UV(gi+3s) into freed B-regs (idx resident)
            {
                int rs_ = rsD, rd_ = rdD;
                uB0 = *(const bf16x8*)(UV + (size_t)rs_ * 256 + (kb0 + 0) * 32 + q * 8);
                uB1 = *(const bf16x8*)(UV + (size_t)rs_ * 256 + (kb0 + 1) * 32 + q * 8);
                vB0 = *(const bf16x8*)(UV + (size_t)rd_ * 256 + 128 + (kb0 + 0) * 32 + q * 8);
                vB1 = *(const bf16x8*)(UV + (size_t)rd_ * 256 + 128 + (kb0 + 1) * 32 + q * 8);
            }
            // idx(gi+5s)
            {
                int g5 = gi + 5 * stride; int gg = g5 < nG ? g5 : 0;
                int e5 = gg * 32 + p2 * 16 + m; if (e5 >= E) e5 = E - 1;
                rsD = src[e5]; rdD = dst[e5];
            }

            asm volatile("s_waitcnt lgkmcnt(0)" ::: "memory");
            __builtin_amdgcn_s_barrier();
            __builtin_amdgcn_sched_barrier(0);

            bf16x8 a0, a1, a2, a3;
            if (hf == 0) {
                a0 = aOwn0;
                a1 = aOwn1;
                a2 = *(const bf16x8*)&aS[1][p2][2][lane][0];
                a3 = *(const bf16x8*)&aS[1][p2][3][lane][0];
            } else {
                a0 = *(const bf16x8*)&aS[1][p2][0][lane][0];
                a1 = *(const bf16x8*)&aS[1][p2][1][lane][0];
                a2 = aOwn0;
                a3 = aOwn1;
            }

            f32x4 acc[4];
#pragma unroll
            for (int i = 0; i < 4; i++) acc[i] = (f32x4){0.f, 0.f, 0.f, 0.f};
#pragma unroll
            for (int i = 0; i < 4; i++) acc[i] = __builtin_amdgcn_mfma_f32_16x16x32_bf16(a0, B1h[i][0], acc[i], 0, 0, 0);
#pragma unroll
            for (int i = 0; i < 4; i++) acc[i] = __builtin_amdgcn_mfma_f32_16x16x32_bf16(a1, B1h[i][1], acc[i], 0, 0, 0);
#pragma unroll
            for (int i = 0; i < 4; i++) acc[i] = __builtin_amdgcn_mfma_f32_16x16x32_bf16(a2, B1h[i][2], acc[i], 0, 0, 0);
#pragma unroll
            for (int i = 0; i < 4; i++) acc[i] = __builtin_amdgcn_mfma_f32_16x16x32_bf16(a3, B1h[i][3], acc[i], 0, 0, 0);

            float s[4] = {0.f, 0.f, 0.f, 0.f};
#pragma unroll
            for (int i = 0; i < 4; i++)
#pragma unroll
                for (int r = 0; r < 4; r++) {
                    float v = acc[i][r] + b1v[i];
                    v = v > 0.f ? v : 0.f;
                    s[r] += v * w2v[i];
                }
#pragma unroll
            for (int off = 1; off < 16; off <<= 1)
#pragma unroll
                for (int r = 0; r < 4; r++) s[r] += __shfl_xor(s[r], off, 16);
            if (m == 0) {
#pragma unroll
                for (int r = 0; r < 4; r++) pS[1][p2][hf][q * 4 + r] = s[r];
            }

            asm volatile("s_waitcnt lgkmcnt(0)" ::: "memory");
            __builtin_amdgcn_s_barrier();
            __builtin_amdgcn_sched_barrier(0);

            if (hf == 0 && lane < 16) {
                int e = gB * 32 + p2 * 16 + lane;
                if (e < E)
                    out[e] = pS[1][p2][0][lane] + pS[1][p2][1][lane] + b2s;
            }
        }
    }
}

// ---------------- launcher ----------------
extern "C" void kernel_launch(void* const* d_in, const int* in_sizes, int n_in,
                              void* d_out, int out_size, void* d_ws, size_t ws_size,
                              hipStream_t stream) {
    const float* h   = (const float*)d_in[0];
    const int*   src = (const int*)d_in[1];
    const int*   dst = (const int*)d_in[2];
    const float* W0  = (const float*)d_in[3];
    const float* b0  = (const float*)d_in[4];
    const float* W1  = (const float*)d_in[5];
    const float* b1  = (const float*)d_in[6];
    const float* W2  = (const float*)d_in[7];
    const float* b2  = (const float*)d_in[8];
    const float* g0  = (const float*)d_in[9];
    const float* be0 = (const float*)d_in[10];
    const float* g1  = (const float*)d_in[11];
    const float* be1 = (const float*)d_in[12];
    const float* g2  = (const float*)d_in[13];
    const float* be2 = (const float*)d_in[14];
    const float* m0  = (const float*)d_in[15];
    const float* v0  = (const float*)d_in[16];
    const float* m1  = (const float*)d_in[17];
    const float* v1  = (const float*)d_in[18];
    const float* m2  = (const float*)d_in[19];
    const float* v2  = (const float*)d_in[20];
    float* out = (float*)d_out;

    const int hsz = in_sizes[0];          // N*128
    const int E   = in_sizes[1];
    const int N   = hsz / 128;

    // ws layout (verified R6-R11): UV f16 (N*256) + weight tail; ~5.22 MB total
    char* ws = (char*)d_ws;
    unsigned short* UV = (unsigned short*)ws;
    size_t off = ((size_t)N * 256 * 2 + 255) & ~(size_t)255;
    unsigned short* W0sw = (unsigned short*)(ws + off);  off += 65536;
    unsigned short* W1sw = (unsigned short*)(ws + off);  off += 32768;
    float* b0f = (float*)(ws + off);  off += 512;
    float* b1f = (float*)(ws + off);  off += 512;
    float* w2f = (float*)(ws + off);  off += 512;
    float* b2f = (float*)(ws + off);  off += 16;

    k_prep<<<320, 256, 0, stream>>>(W0, b0, W1, b1, W2, b2,
                                    g0, be0, m0, v0, g1, be1, m1, v1,
                                    g2, be2, m2, v2,
                                    W0sw, W1sw, b0f, b1f, w2f, b2f);

    int nodeBlocks = (N + 31) / 32;
    k_node<<<nodeBlocks, 256, 0, stream>>>(h, W0sw, b0f, UV, N);

    int nG = (E + 31) / 32;                 // 32 edges per group (2 pairs x 16)
    int nBlocks = nG < 768 ? nG : 768;      // 3 blocks/CU (LDS 16.5 KB, target <=170 VGPR)
    k_edge<<<nBlocks, 256, 0, stream>>>(src, dst, UV, W1sw,
                                        b1f, w2f, b2f, out, E, nG);
}

// Round 13
// 135.094 us; speedup vs baseline: 1.0592x; 1.0592x over previous
//
#include <hip/hip_runtime.h>
#include <hip/hip_bf16.h>

#define BN_EPS 1e-5f
#define MG 2                 // 16-node tiles per k_node block

typedef short bf16x8 __attribute__((ext_vector_type(8)));   // also generic short8
typedef float f32x4  __attribute__((ext_vector_type(4)));

static __device__ __forceinline__ unsigned short f2bf(float f) {
    union { float f; unsigned int u; } v; v.f = f;
    unsigned int u = v.u;
    unsigned int r = (u + 0x7FFFu + ((u >> 16) & 1u)) >> 16;   // RNE
    return (unsigned short)r;
}

static __device__ __forceinline__ unsigned short f2bf_hw(float f) {
    __hip_bfloat16 b = __float2bfloat16(f);
    union { __hip_bfloat16 b; unsigned short u; } v; v.b = b;
    return v.u;
}

static __device__ __forceinline__ unsigned short f2h(float f) {   // f32 -> f16 bits (RNE)
    union { _Float16 h; unsigned short u; } v; v.h = (_Float16)f;
    return v.u;
}

static __device__ __forceinline__ float h2f(short s) {            // f16 bits -> f32
    union { short s; _Float16 h; } v; v.s = s;
    return (float)v.h;
}

// ---------------- prep kernel: weights only ----------------
__global__ __launch_bounds__(256) void k_prep(
        const float* __restrict__ W0, const float* __restrict__ b0,
        const float* __restrict__ W1, const float* __restrict__ b1,
        const float* __restrict__ W2, const float* __restrict__ b2,
        const float* __restrict__ g0, const float* __restrict__ be0,
        const float* __restrict__ m0, const float* __restrict__ v0,
        const float* __restrict__ g1, const float* __restrict__ be1,
        const float* __restrict__ m1, const float* __restrict__ v1,
        const float* __restrict__ g2, const float* __restrict__ be2,
        const float* __restrict__ m2, const float* __restrict__ v2,
        unsigned short* __restrict__ W0sw, unsigned short* __restrict__ W1sw,
        float* __restrict__ b0f, float* __restrict__ b1f,
        float* __restrict__ w2f, float* __restrict__ b2f) {
    int br = blockIdx.x;
    const int tid = threadIdx.x;

    if (br < 128) {                        // ---- W0sw (BN0 scale folded) ----
        int t = br * 256 + tid;
        int j = t & 7, lane = (t >> 3) & 63, nt = (t >> 9) & 7, kb = t >> 12;
        int k = kb * 32 + (lane >> 4) * 8 + j;
        int n = nt * 16 + (lane & 15);
        float s = g0[k] * rsqrtf(v0[k] + BN_EPS);
        W0sw[t] = f2bf(W0[n * 256 + k] * s);
        return;
    }
    br -= 128;
    if (br < 64) {                         // ---- W1sw ----
        int t = br * 256 + tid;
        int j = t & 7, lane = (t >> 3) & 63, nt = (t >> 9) & 7, kb = t >> 12;
        int k = kb * 32 + (lane >> 4) * 8 + j;
        int n = nt * 16 + (lane & 15);
        float s = g1[k] * rsqrtf(v1[k] + BN_EPS);
        W1sw[t] = f2bf(W1[n * 128 + k] * s);
        return;
    }
    br -= 64;
    {                                      // ---- folded biases (row = br, 0..127) ----
        if (tid >= 64) return;
        const int i = br, lane = tid;
        float s0 = 0.f;
#pragma unroll
        for (int c = 0; c < 4; c++) {
            int k = c * 64 + lane;
            float sc = g0[k] * rsqrtf(v0[k] + BN_EPS);
            s0 += W0[i * 256 + k] * (be0[k] - m0[k] * sc);
        }
        float s1 = 0.f;
#pragma unroll
        for (int c = 0; c < 2; c++) {
            int k = c * 64 + lane;
            float sc = g1[k] * rsqrtf(v1[k] + BN_EPS);
            s1 += W1[i * 128 + k] * (be1[k] - m1[k] * sc);
        }
        float s2 = 0.f;
        if (i == 0) {
#pragma unroll
            for (int c = 0; c < 2; c++) {
                int k = c * 64 + lane;
                float sc = g2[k] * rsqrtf(v2[k] + BN_EPS);
                s2 += W2[k] * (be2[k] - m2[k] * sc);
            }
        }
#pragma unroll
        for (int off = 1; off < 64; off <<= 1) {
            s0 += __shfl_xor(s0, off);
            s1 += __shfl_xor(s1, off);
            s2 += __shfl_xor(s2, off);
        }
        if (lane == 0) {
            b0f[i] = b0[i] + s0;
            b1f[i] = b1[i] + s1;
            w2f[i] = W2[i] * (g2[i] * rsqrtf(v2[i] + BN_EPS));
            if (i == 0) b2f[0] = b2[0] + s2;
        }
    }
}

// ---------------- node projection: UV[n][0..127]=f16(h@W0s^T+b0f), [128..255]=f16(h@W0d^T) ----
__global__ __launch_bounds__(256) void k_node(
        const float* __restrict__ h,
        const unsigned short* __restrict__ W0sw,
        const float* __restrict__ b0f,
        unsigned short* __restrict__ UV, int N) {
    const int tid  = threadIdx.x;
    const int wave = tid >> 6;
    const int lane = tid & 63;
    const int quad = lane >> 4;
    const int m    = lane & 15;
    const int nb   = blockIdx.x * 32;

    bf16x8 B0[8][2];
#pragma unroll
    for (int kb = 0; kb < 8; kb++)
#pragma unroll
        for (int hh = 0; hh < 2; hh++)
            B0[kb][hh] = *(const bf16x8*)(W0sw + ((kb * 8 + (wave * 2 + hh)) * 64 + lane) * 8);

    float b0v[2];
#pragma unroll
    for (int hh = 0; hh < 2; hh++) b0v[hh] = b0f[(wave * 2 + hh) * 16 + m];

    f32x4 au[MG][2], av[MG][2];
#pragma unroll
    for (int g = 0; g < MG; g++)
#pragma unroll
        for (int hh = 0; hh < 2; hh++) {
            au[g][hh] = (f32x4){0.f, 0.f, 0.f, 0.f};
            av[g][hh] = (f32x4){0.f, 0.f, 0.f, 0.f};
        }

#pragma unroll
    for (int g = 0; g < MG; g++) {
        int nrow = nb + g * 16 + m; if (nrow >= N) nrow = N - 1;
        const float* hrow = h + (size_t)nrow * 128;
#pragma unroll
        for (int kb = 0; kb < 4; kb++) {
            const float* hp = hrow + kb * 32 + quad * 8;
            f32x4 f0 = *(const f32x4*)hp;
            f32x4 f1 = *(const f32x4*)(hp + 4);
            bf16x8 a;
            a[0] = (short)f2bf_hw(f0[0]); a[1] = (short)f2bf_hw(f0[1]);
            a[2] = (short)f2bf_hw(f0[2]); a[3] = (short)f2bf_hw(f0[3]);
            a[4] = (short)f2bf_hw(f1[0]); a[5] = (short)f2bf_hw(f1[1]);
            a[6] = (short)f2bf_hw(f1[2]); a[7] = (short)f2bf_hw(f1[3]);
#pragma unroll
            for (int hh = 0; hh < 2; hh++) {
                au[g][hh] = __builtin_amdgcn_mfma_f32_16x16x32_bf16(a, B0[kb][hh],     au[g][hh], 0, 0, 0);
                av[g][hh] = __builtin_amdgcn_mfma_f32_16x16x32_bf16(a, B0[kb + 4][hh], av[g][hh], 0, 0, 0);
            }
        }
    }

#pragma unroll
    for (int g = 0; g < MG; g++)
#pragma unroll
        for (int hh = 0; hh < 2; hh++) {
            int col = (wave * 2 + hh) * 16 + m;
#pragma unroll
            for (int r = 0; r < 4; r++) {
                int node = nb + g * 16 + quad * 4 + r;
                if (node < N) {
                    UV[(size_t)node * 256 + col]       = f2h(au[g][hh][r] + b0v[hh]);
                    UV[(size_t)node * 256 + 128 + col] = f2h(av[g][hh][r]);
                }
            }
        }
}

// ---------------- edge kernel: barrier-free, wave-independent (R8 revert — session best) ----
// R12 verdict: six structural variants (barrier'd/barrier-free, 8-12 waves/CU, 1/2-deep
// prefetch) all pin k_edge at ~36 us. The invariant: 164 MB random gather against the
// 5.12 MB UV table (> 4 MB per-XCD L2) -> ~28 MB L2-miss traffic at the ~700-780 GB/s
// random-line rate ~= 36 us. Throughput wall of the memory system, not scheduling.
// Each wave owns 16 edges end-to-end: A-frag (lane l <- edge l&15, k=kb*32+(l>>4)*8+j)
// gathered per-lane from UV, f32 add -> relu -> bf16 in-register. B1 full-width per wave
// (128 VGPR). No LDS, no barriers. ~240 VGPR -> (256,2), grid 512 exact-resident.
__global__ __launch_bounds__(256, 2) void k_edge(
        const int* __restrict__ src, const int* __restrict__ dst,
        const unsigned short* __restrict__ UV,
        const unsigned short* __restrict__ W1sw,
        const float* __restrict__ b1f, const float* __restrict__ w2f,
        const float* __restrict__ b2fp,
        float* __restrict__ out, int E, int nG) {
    const int tid  = threadIdx.x;
    const int wave = tid >> 6;
    const int lane = tid & 63;
    const int q    = lane >> 4;
    const int m    = lane & 15;

    // full stage-1 weights per wave: nt 0..7, kb 0..3 (128 VGPR)
    bf16x8 B1f[8][4];
#pragma unroll
    for (int nt = 0; nt < 8; nt++)
#pragma unroll
        for (int kb = 0; kb < 4; kb++)
            B1f[nt][kb] = *(const bf16x8*)(W1sw + ((kb * 8 + nt) * 64 + lane) * 8);

    float b1v[8], w2v[8];
#pragma unroll
    for (int nt = 0; nt < 8; nt++) {
        b1v[nt] = b1f[nt * 16 + m];
        w2v[nt] = w2f[nt * 16 + m];
    }
    const float b2s = *b2fp;
    const int stride = gridDim.x;

    int gi = blockIdx.x;
    bf16x8 uF[4], vF[4];        // raw f16 UV chunks for group t (this lane's A-frag data)
    int rsC, rdC;               // node indices for group t+1 (resident)

    // ---- prologue: idx(t0) -> UV(t0) issue; idx(t1) ----
    {
        int e0 = gi * 64 + wave * 16 + m; if (e0 >= E) e0 = E - 1;
        int rs0 = src[e0], rd0 = dst[e0];
#pragma unroll
        for (int kb = 0; kb < 4; kb++) {
            uF[kb] = *(const bf16x8*)(UV + (size_t)rs0 * 256 + kb * 32 + q * 8);
            vF[kb] = *(const bf16x8*)(UV + (size_t)rd0 * 256 + 128 + kb * 32 + q * 8);
        }
        int g1 = gi + stride;
        int e1 = (g1 < nG ? g1 : gi) * 64 + wave * 16 + m; if (e1 >= E) e1 = E - 1;
        rsC = src[e1]; rdC = dst[e1];
    }

    for (; gi < nG; gi += stride) {
        // ---- build A-frags: a[kb][j] = bf16(relu(f32(u)+f32(v))) ----
        bf16x8 a[4];
#pragma unroll
        for (int kb = 0; kb < 4; kb++)
#pragma unroll
            for (int j = 0; j < 8; j++) {
                float s = h2f(uF[kb][j]) + h2f(vF[kb][j]);
                s = s > 0.f ? s : 0.f;
                a[kb][j] = (short)f2bf_hw(s);
            }

        // ---- issue UV(t+1) into now-dead uF/vF (indices resident); covered by MFMA+stage2 ----
        {
            int rs_ = rsC, rd_ = rdC;
#pragma unroll
            for (int kb = 0; kb < 4; kb++) {
                uF[kb] = *(const bf16x8*)(UV + (size_t)rs_ * 256 + kb * 32 + q * 8);
                vF[kb] = *(const bf16x8*)(UV + (size_t)rd_ * 256 + 128 + kb * 32 + q * 8);
            }
        }
        // ---- issue idx(t+2) ----
        {
            int g2 = gi + 2 * stride;
            int e2 = (g2 < nG ? g2 : gi) * 64 + wave * 16 + m; if (e2 >= E) e2 = E - 1;
            rsC = src[e2]; rdC = dst[e2];
        }

        // ---- stage 1: 32 MFMA (8 independent acc chains) ----
        f32x4 acc[8];
#pragma unroll
        for (int nt = 0; nt < 8; nt++) acc[nt] = (f32x4){0.f, 0.f, 0.f, 0.f};
#pragma unroll
        for (int kb = 0; kb < 4; kb++)
#pragma unroll
            for (int nt = 0; nt < 8; nt++)
                acc[nt] = __builtin_amdgcn_mfma_f32_16x16x32_bf16(a[kb], B1f[nt][kb], acc[nt], 0, 0, 0);

        // ---- stage 2: relu(x2 + b1) . w2, reduce over the 16 feature-lanes ----
        float s[4] = {0.f, 0.f, 0.f, 0.f};
#pragma unroll
        for (int nt = 0; nt < 8; nt++)
#pragma unroll
            for (int r = 0; r < 4; r++) {
                float v = acc[nt][r] + b1v[nt];
                v = v > 0.f ? v : 0.f;
                s[r] += v * w2v[nt];
            }
#pragma unroll
        for (int off = 1; off < 16; off <<= 1)
#pragma unroll
            for (int r = 0; r < 4; r++) s[r] += __shfl_xor(s[r], off, 16);

        if (m == 0) {
            int eB = gi * 64 + wave * 16 + q * 4;
#pragma unroll
            for (int r = 0; r < 4; r++) {
                int e = eB + r;
                if (e < E) out[e] = s[r] + b2s;
            }
        }
    }
}

// ---------------- launcher ----------------
extern "C" void kernel_launch(void* const* d_in, const int* in_sizes, int n_in,
                              void* d_out, int out_size, void* d_ws, size_t ws_size,
                              hipStream_t stream) {
    const float* h   = (const float*)d_in[0];
    const int*   src = (const int*)d_in[1];
    const int*   dst = (const int*)d_in[2];
    const float* W0  = (const float*)d_in[3];
    const float* b0  = (const float*)d_in[4];
    const float* W1  = (const float*)d_in[5];
    const float* b1  = (const float*)d_in[6];
    const float* W2  = (const float*)d_in[7];
    const float* b2  = (const float*)d_in[8];
    const float* g0  = (const float*)d_in[9];
    const float* be0 = (const float*)d_in[10];
    const float* g1  = (const float*)d_in[11];
    const float* be1 = (const float*)d_in[12];
    const float* g2  = (const float*)d_in[13];
    const float* be2 = (const float*)d_in[14];
    const float* m0  = (const float*)d_in[15];
    const float* v0  = (const float*)d_in[16];
    const float* m1  = (const float*)d_in[17];
    const float* v1  = (const float*)d_in[18];
    const float* m2  = (const float*)d_in[19];
    const float* v2  = (const float*)d_in[20];
    float* out = (float*)d_out;

    const int hsz = in_sizes[0];          // N*128
    const int E   = in_sizes[1];
    const int N   = hsz / 128;

    // ws layout (verified R6-R12): UV f16 (N*256) + weight tail; ~5.22 MB total
    char* ws = (char*)d_ws;
    unsigned short* UV = (unsigned short*)ws;
    size_t off = ((size_t)N * 256 * 2 + 255) & ~(size_t)255;
    unsigned short* W0sw = (unsigned short*)(ws + off);  off += 65536;
    unsigned short* W1sw = (unsigned short*)(ws + off);  off += 32768;
    float* b0f = (float*)(ws + off);  off += 512;
    float* b1f = (float*)(ws + off);  off += 512;
    float* w2f = (float*)(ws + off);  off += 512;
    float* b2f = (float*)(ws + off);  off += 16;

    k_prep<<<320, 256, 0, stream>>>(W0, b0, W1, b1, W2, b2,
                                    g0, be0, m0, v0, g1, be1, m1, v1,
                                    g2, be2, m2, v2,
                                    W0sw, W1sw, b0f, b1f, w2f, b2f);

    int nodeBlocks = (N + 31) / 32;
    k_node<<<nodeBlocks, 256, 0, stream>>>(h, W0sw, b0f, UV, N);

    int nG = (E + 63) / 64;                 // 64 edges per block (4 waves x 16)
    int nBlocks = nG < 512 ? nG : 512;      // 2 blocks/CU exact-resident (0 LDS, ~240 VGPR)
    k_edge<<<nBlocks, 256, 0, stream>>>(src, dst, UV, W1sw,
                                        b1f, w2f, b2f, out, E, nG);
}